// Round 1
// baseline (550.369 us; speedup 1.0000x reference)
//
#include <hip/hip_runtime.h>
#include <cstdint>

typedef unsigned short u16;
typedef __attribute__((ext_vector_type(4))) float f32x4;
typedef __attribute__((ext_vector_type(4))) unsigned short u16x4;
typedef __attribute__((ext_vector_type(8))) unsigned short u16x8;
typedef __attribute__((ext_vector_type(8))) __bf16 bf16x8;

#define DEV __device__ __forceinline__

DEV u16 f2bf(float f) {
  union { float f; uint32_t u; } x{f};
  uint32_t r = (x.u + 0x7fffu + ((x.u >> 16) & 1u)) >> 16;
  return (u16)r;
}
DEV float bf2f(u16 u) {
  union { uint32_t u; float f; } x{(uint32_t)u << 16};
  return x.f;
}

// async global->LDS, 16B per lane; LDS dest semantics: wave-uniform base + lane*16
DEV void gl_lds16(const void* g, void* l) {
  __builtin_amdgcn_global_load_lds((__attribute__((address_space(1))) void*)(g),
                                   (__attribute__((address_space(3))) void*)(l),
                                   16, 0, 0);
}

// ---------------------------------------------------------------- cast x -> bf16
__global__ __launch_bounds__(256) void cast_f2b(const float* __restrict__ in,
                                                u16* __restrict__ out) {
  int i = blockIdx.x * 256 + threadIdx.x;
  float4 v = ((const float4*)in)[i];
  u16x4 o = { f2bf(v.x), f2bf(v.y), f2bf(v.z), f2bf(v.w) };
  ((u16x4*)out)[i] = o;
}

// ------------------------------------------- transpose + cast weights: out[c][r] = in[r][c]
__global__ __launch_bounds__(256) void transpose_cast(const float* __restrict__ in,
                                                      u16* __restrict__ out, int R, int C) {
  __shared__ float tile[64][65];
  const int c0 = blockIdx.x * 64, r0 = blockIdx.y * 64;
  const int tx = threadIdx.x & 63, ty = threadIdx.x >> 6;
  for (int r = ty; r < 64; r += 4) tile[r][tx] = in[(size_t)(r0 + r) * C + c0 + tx];
  __syncthreads();
  for (int r = ty; r < 64; r += 4) out[(size_t)(c0 + r) * R + r0 + tx] = f2bf(tile[tx][r]);
}

// ------------------------------------------------------------- MFMA GEMM (A row-major, Bt row-major = B^T)
// EPI 0: C[8192][3072] -> split q/k/v bf16 head-major [BH][T][64]
// EPI 1: C[8192][1024] -> fp32 out
template <int EPI>
__global__ __launch_bounds__(256) void gemm_bt(const u16* __restrict__ A,
                                               const u16* __restrict__ Bt,
                                               u16* __restrict__ qo, u16* __restrict__ ko,
                                               u16* __restrict__ vo, float* __restrict__ outf) {
  const int K = 1024;
  __shared__ __align__(16) u16 As[128 * 32];
  __shared__ __align__(16) u16 Bs[128 * 32];
  const int m0 = blockIdx.y * 128, n0 = blockIdx.x * 128;
  const int tid = threadIdx.x;
  const int w = tid >> 6, lane = tid & 63, quad = lane >> 4, l15 = lane & 15;
  const int mw = (w >> 1) * 64, nw = (w & 1) * 64;
  const int srow = lane >> 2, scol = (lane & 3) * 8;

  f32x4 acc[4][4];
#pragma unroll
  for (int i = 0; i < 4; ++i)
#pragma unroll
    for (int j = 0; j < 4; ++j) acc[i][j] = f32x4{0.f, 0.f, 0.f, 0.f};

  const u16* ga0 = A + (size_t)(m0 + srow) * K + scol;
  const u16* gb0 = Bt + (size_t)(n0 + srow) * K + scol;

  for (int k0 = 0; k0 < K; k0 += 32) {
#pragma unroll
    for (int cc = 0; cc < 2; ++cc) {
      int c = w + cc * 4;
      gl_lds16(ga0 + (size_t)c * 16 * K + k0, As + c * 512 + lane * 8);
      gl_lds16(gb0 + (size_t)c * 16 * K + k0, Bs + c * 512 + lane * 8);
    }
    __syncthreads();
    bf16x8 af[4], bfv[4];
#pragma unroll
    for (int i = 0; i < 4; ++i)
      af[i] = *(const bf16x8*)(As + (mw + i * 16 + l15) * 32 + quad * 8);
#pragma unroll
    for (int j = 0; j < 4; ++j)
      bfv[j] = *(const bf16x8*)(Bs + (nw + j * 16 + l15) * 32 + quad * 8);
#pragma unroll
    for (int i = 0; i < 4; ++i)
#pragma unroll
      for (int j = 0; j < 4; ++j)
        acc[i][j] = __builtin_amdgcn_mfma_f32_16x16x32_bf16(af[i], bfv[j], acc[i][j], 0, 0, 0);
    __syncthreads();
  }

  // epilogue: C/D layout col = lane&15, row = quad*4 + r (verified m89/m91)
#pragma unroll
  for (int i = 0; i < 4; ++i)
#pragma unroll
    for (int j = 0; j < 4; ++j)
#pragma unroll
      for (int r = 0; r < 4; ++r) {
        int row = m0 + mw + i * 16 + quad * 4 + r;
        int col = n0 + nw + j * 16 + l15;
        if (EPI == 0) {
          int b = row >> 11, t = row & 2047;
          int s = col >> 10, rem = col & 1023;
          int h = rem >> 6, d = rem & 63;
          size_t idx = ((size_t)(b * 16 + h) * 2048 + t) * 64 + d;
          u16 bits = f2bf(acc[i][j][r]);
          if (s == 0) qo[idx] = bits;
          else if (s == 1) ko[idx] = bits;
          else vo[idx] = bits;
        } else {
          outf[(size_t)row * 1024 + col] = acc[i][j][r];
        }
      }
}

// ---------------------------------------------------------------- RoPE (in-place on q,k)
__global__ __launch_bounds__(256) void rope_kernel(u16* __restrict__ q, u16* __restrict__ k) {
  const int tx = threadIdx.x & 31, ty = threadIdx.x >> 5;
  const int t = blockIdx.x * 8 + ty;
  const int bh = blockIdx.y;
  float inv = powf(10000.f, -(float)tx * (1.f / 32.f));
  float ang = (float)t * inv;
  float s, c;
  sincosf(ang, &s, &c);
  size_t base = ((size_t)bh * 2048 + t) * 64;
  float a1 = bf2f(q[base + tx]), a2 = bf2f(q[base + tx + 32]);
  q[base + tx] = f2bf(a1 * c - a2 * s);
  q[base + tx + 32] = f2bf(a2 * c + a1 * s);
  float b1 = bf2f(k[base + tx]), b2 = bf2f(k[base + tx + 32]);
  k[base + tx] = f2bf(b1 * c - b2 * s);
  k[base + tx + 32] = f2bf(b2 * c + b1 * s);
}

// ------------------------------------------------- V transpose: [BH][T][64] -> [BH][64][T]
__global__ __launch_bounds__(256) void transpose_v(const u16* __restrict__ v,
                                                   u16* __restrict__ vt) {
  const int bh = blockIdx.y, t0 = blockIdx.x * 64;
  __shared__ __align__(16) u16 tile[64][72];
  const int tid = threadIdx.x;
  const int row = tid >> 3, col = (tid & 7) * 8;
#pragma unroll
  for (int rr = 0; rr < 2; ++rr) {
    int r = row + rr * 32;
    *(u16x8*)(&tile[r][col]) = *(const u16x8*)(v + ((size_t)bh * 2048 + t0 + r) * 64 + col);
  }
  __syncthreads();
#pragma unroll
  for (int rr = 0; rr < 2; ++rr) {
    int d = row + rr * 32;
    u16x8 o;
#pragma unroll
    for (int j = 0; j < 8; ++j) o[j] = tile[col + j][d];
    *(u16x8*)(vt + ((size_t)bh * 64 + d) * 2048 + t0 + col) = o;
  }
}

// --------------------------------------------------------- flash attention (causal)
// grid (T/64, BH), 4 waves; wave w owns Q rows q0+w*16..+15; 32-key iterations
__global__ __launch_bounds__(256) void attn_kernel(const u16* __restrict__ q,
                                                   const u16* __restrict__ k,
                                                   const u16* __restrict__ vt,
                                                   u16* __restrict__ y) {
  const int T = 2048;
  const int bh = blockIdx.y;
  const int q0 = blockIdx.x * 64;
  const int tid = threadIdx.x;
  const int w = tid >> 6, lane = tid & 63, quad = lane >> 4, l15 = lane & 15;
  __shared__ __align__(16) u16 Ks[32 * 64];  // [key][d]
  __shared__ __align__(16) u16 Vs[64 * 32];  // [d][key]
  __shared__ __align__(16) u16 Ps[4 * 16 * 32];  // per-wave P [16 q][32 key]

  const int qrow = q0 + w * 16 + l15;
  const u16* qp = q + ((size_t)bh * T + qrow) * 64;
  bf16x8 qf0 = *(const bf16x8*)(qp + quad * 8);
  bf16x8 qf1 = *(const bf16x8*)(qp + 32 + quad * 8);

  f32x4 o[4];
  float mi[4], li[4];
  int qg[4];
#pragma unroll
  for (int r = 0; r < 4; ++r) {
    o[r] = f32x4{0.f, 0.f, 0.f, 0.f};
    mi[r] = -__builtin_inff();
    li[r] = 0.f;
    qg[r] = q0 + w * 16 + quad * 4 + r;
  }

  const int nkt = q0 / 32 + 2;  // keys 0 .. q0+63
  const int krow = tid >> 3, kc8 = (tid & 7) * 8;
  const int vd = tid >> 2, vc8 = (tid & 3) * 8;

  for (int kt = 0; kt < nkt; ++kt) {
    const int kb = kt * 32;
    *(u16x8*)(Ks + tid * 8) = *(const u16x8*)(k + ((size_t)bh * T + kb + krow) * 64 + kc8);
    *(u16x8*)(Vs + tid * 8) = *(const u16x8*)(vt + ((size_t)bh * 64 + vd) * T + kb + vc8);
    __syncthreads();

    bf16x8 k00 = *(const bf16x8*)(Ks + l15 * 64 + quad * 8);
    bf16x8 k01 = *(const bf16x8*)(Ks + l15 * 64 + 32 + quad * 8);
    bf16x8 k10 = *(const bf16x8*)(Ks + (16 + l15) * 64 + quad * 8);
    bf16x8 k11 = *(const bf16x8*)(Ks + (16 + l15) * 64 + 32 + quad * 8);
    f32x4 s0 = f32x4{0.f, 0.f, 0.f, 0.f}, s1 = f32x4{0.f, 0.f, 0.f, 0.f};
    s0 = __builtin_amdgcn_mfma_f32_16x16x32_bf16(qf0, k00, s0, 0, 0, 0);
    s0 = __builtin_amdgcn_mfma_f32_16x16x32_bf16(qf1, k01, s0, 0, 0, 0);
    s1 = __builtin_amdgcn_mfma_f32_16x16x32_bf16(qf0, k10, s1, 0, 0, 0);
    s1 = __builtin_amdgcn_mfma_f32_16x16x32_bf16(qf1, k11, s1, 0, 0, 0);

    const int key0 = kb + l15, key1 = kb + 16 + l15;
    float alpha[4], p0[4], p1[4];
#pragma unroll
    for (int r = 0; r < 4; ++r) {
      float a = (key0 <= qg[r]) ? s0[r] * 0.125f : -__builtin_inff();
      float b2 = (key1 <= qg[r]) ? s1[r] * 0.125f : -__builtin_inff();
      float mr = fmaxf(a, b2);
#pragma unroll
      for (int off = 8; off > 0; off >>= 1) mr = fmaxf(mr, __shfl_xor(mr, off, 64));
      float mn = fmaxf(mi[r], mr);
      alpha[r] = __expf(mi[r] - mn);
      p0[r] = __expf(a - mn);
      p1[r] = __expf(b2 - mn);
      float rs = p0[r] + p1[r];
#pragma unroll
      for (int off = 8; off > 0; off >>= 1) rs += __shfl_xor(rs, off, 64);
      li[r] = li[r] * alpha[r] + rs;
      mi[r] = mn;
    }
#pragma unroll
    for (int dt = 0; dt < 4; ++dt)
#pragma unroll
      for (int r = 0; r < 4; ++r) o[dt][r] *= alpha[r];

    // P: C-layout -> LDS -> A-layout (verified m120 transform)
#pragma unroll
    for (int r = 0; r < 4; ++r) {
      Ps[w * 512 + (quad * 4 + r) * 32 + l15] = f2bf(p0[r]);
      Ps[w * 512 + (quad * 4 + r) * 32 + 16 + l15] = f2bf(p1[r]);
    }
    __syncthreads();
    bf16x8 pf = *(const bf16x8*)(Ps + w * 512 + l15 * 32 + quad * 8);
#pragma unroll
    for (int dt = 0; dt < 4; ++dt) {
      bf16x8 vf = *(const bf16x8*)(Vs + (dt * 16 + l15) * 32 + quad * 8);
      o[dt] = __builtin_amdgcn_mfma_f32_16x16x32_bf16(pf, vf, o[dt], 0, 0, 0);
    }
    __syncthreads();
  }

  const int b = bh >> 4, h = bh & 15;
#pragma unroll
  for (int r = 0; r < 4; ++r) {
    float inv = 1.f / li[r];
    int trow = q0 + w * 16 + quad * 4 + r;
    size_t base = ((size_t)b * 2048 + trow) * 1024 + h * 64;
#pragma unroll
    for (int dt = 0; dt < 4; ++dt) y[base + dt * 16 + l15] = f2bf(o[dt][r] * inv);
  }
}

extern "C" void kernel_launch(void* const* d_in, const int* in_sizes, int n_in,
                              void* d_out, int out_size, void* d_ws, size_t ws_size,
                              hipStream_t stream) {
  const float* x = (const float*)d_in[0];
  const float* w_qkv = (const float*)d_in[1];
  const float* w_proj = (const float*)d_in[2];
  float* out = (float*)d_out;

  u16* xb = (u16*)d_ws;            // 8192*1024 bf16 (x), later reused as y
  u16* wqkvT = xb + 8388608;       // 3072*1024
  u16* wprojT = wqkvT + 3145728;   // 1024*1024
  u16* qb = wprojT + 1048576;      // [64][2048][64]
  u16* kbuf = qb + 8388608;
  u16* vb = kbuf + 8388608;
  u16* vtb = vb + 8388608;         // [64][64][2048]
  u16* yb = xb;                    // alias: xb fully consumed by gemm1 before attn writes y

  cast_f2b<<<8192, 256, 0, stream>>>(x, xb);
  transpose_cast<<<dim3(48, 16), 256, 0, stream>>>(w_qkv, wqkvT, 1024, 3072);
  transpose_cast<<<dim3(16, 16), 256, 0, stream>>>(w_proj, wprojT, 1024, 1024);
  gemm_bt<0><<<dim3(24, 64), 256, 0, stream>>>(xb, wqkvT, qb, kbuf, vb, nullptr);
  rope_kernel<<<dim3(256, 64), 256, 0, stream>>>(qb, kbuf);
  transpose_v<<<dim3(32, 64), 256, 0, stream>>>(vb, vtb);
  attn_kernel<<<dim3(32, 64), 256, 0, stream>>>(qb, kbuf, vtb, yb);
  gemm_bt<1><<<dim3(8, 64), 256, 0, stream>>>(yb, wprojT, nullptr, nullptr, nullptr, out);
}

// Round 2
// 310.901 us; speedup vs baseline: 1.7702x; 1.7702x over previous
//
#include <hip/hip_runtime.h>
#include <cstdint>

typedef unsigned short u16;
typedef __attribute__((ext_vector_type(4))) float f32x4;
typedef __attribute__((ext_vector_type(4))) unsigned short u16x4;
typedef __attribute__((ext_vector_type(8))) unsigned short u16x8;
typedef __attribute__((ext_vector_type(8))) __bf16 bf16x8;

#define DEV __device__ __forceinline__

DEV u16 f2bf(float f) {
  union { float f; uint32_t u; } x{f};
  uint32_t r = (x.u + 0x7fffu + ((x.u >> 16) & 1u)) >> 16;
  return (u16)r;
}
DEV float bf2f(u16 u) {
  union { uint32_t u; float f; } x{(uint32_t)u << 16};
  return x.f;
}

// async global->LDS, 16B per lane; LDS dest semantics: wave-uniform base + lane*16
DEV void gl_lds16(const void* g, void* l) {
  __builtin_amdgcn_global_load_lds((__attribute__((address_space(1))) void*)(g),
                                   (__attribute__((address_space(3))) void*)(l),
                                   16, 0, 0);
}

// ---------------------------------------------------------------- cast x -> bf16
__global__ __launch_bounds__(256) void cast_f2b(const float* __restrict__ in,
                                                u16* __restrict__ out) {
  int i = blockIdx.x * 256 + threadIdx.x;
  float4 v = ((const float4*)in)[i];
  u16x4 o = { f2bf(v.x), f2bf(v.y), f2bf(v.z), f2bf(v.w) };
  ((u16x4*)out)[i] = o;
}

// ------------------------------------------- transpose + cast weights: out[c][r] = in[r][c]
__global__ __launch_bounds__(256) void transpose_cast(const float* __restrict__ in,
                                                      u16* __restrict__ out, int R, int C) {
  __shared__ float tile[64][65];
  const int c0 = blockIdx.x * 64, r0 = blockIdx.y * 64;
  const int tx = threadIdx.x & 63, ty = threadIdx.x >> 6;
  for (int r = ty; r < 64; r += 4) tile[r][tx] = in[(size_t)(r0 + r) * C + c0 + tx];
  __syncthreads();
  for (int r = ty; r < 64; r += 4) out[(size_t)(c0 + r) * R + r0 + tx] = f2bf(tile[tx][r]);
}

// ------------------------------------------------------------- MFMA GEMM (A row-major, Bt row-major = B^T)
// EPI 0: C[8192][3072] -> split q/k/v bf16 head-major [BH][T][64]
// EPI 1: C[8192][1024] -> fp32 out
template <int EPI>
__global__ __launch_bounds__(256) void gemm_bt(const u16* __restrict__ A,
                                               const u16* __restrict__ Bt,
                                               u16* __restrict__ qo, u16* __restrict__ ko,
                                               u16* __restrict__ vo, float* __restrict__ outf) {
  const int K = 1024;
  __shared__ __align__(16) u16 As[128 * 32];
  __shared__ __align__(16) u16 Bs[128 * 32];
  const int m0 = blockIdx.y * 128, n0 = blockIdx.x * 128;
  const int tid = threadIdx.x;
  const int w = tid >> 6, lane = tid & 63, quad = lane >> 4, l15 = lane & 15;
  const int mw = (w >> 1) * 64, nw = (w & 1) * 64;
  const int srow = lane >> 2, scol = (lane & 3) * 8;

  f32x4 acc[4][4];
#pragma unroll
  for (int i = 0; i < 4; ++i)
#pragma unroll
    for (int j = 0; j < 4; ++j) acc[i][j] = f32x4{0.f, 0.f, 0.f, 0.f};

  const u16* ga0 = A + (size_t)(m0 + srow) * K + scol;
  const u16* gb0 = Bt + (size_t)(n0 + srow) * K + scol;

  for (int k0 = 0; k0 < K; k0 += 32) {
#pragma unroll
    for (int cc = 0; cc < 2; ++cc) {
      int c = w + cc * 4;
      gl_lds16(ga0 + (size_t)c * 16 * K + k0, As + c * 512 + lane * 8);
      gl_lds16(gb0 + (size_t)c * 16 * K + k0, Bs + c * 512 + lane * 8);
    }
    __syncthreads();
    bf16x8 af[4], bfv[4];
#pragma unroll
    for (int i = 0; i < 4; ++i)
      af[i] = *(const bf16x8*)(As + (mw + i * 16 + l15) * 32 + quad * 8);
#pragma unroll
    for (int j = 0; j < 4; ++j)
      bfv[j] = *(const bf16x8*)(Bs + (nw + j * 16 + l15) * 32 + quad * 8);
#pragma unroll
    for (int i = 0; i < 4; ++i)
#pragma unroll
      for (int j = 0; j < 4; ++j)
        acc[i][j] = __builtin_amdgcn_mfma_f32_16x16x32_bf16(af[i], bfv[j], acc[i][j], 0, 0, 0);
    __syncthreads();
  }

  // epilogue: C/D layout col = lane&15, row = quad*4 + r (verified m89/m91)
#pragma unroll
  for (int i = 0; i < 4; ++i)
#pragma unroll
    for (int j = 0; j < 4; ++j)
#pragma unroll
      for (int r = 0; r < 4; ++r) {
        int row = m0 + mw + i * 16 + quad * 4 + r;
        int col = n0 + nw + j * 16 + l15;
        if (EPI == 0) {
          int b = row >> 11, t = row & 2047;
          int s = col >> 10, rem = col & 1023;
          int h = rem >> 6, d = rem & 63;
          size_t idx = ((size_t)(b * 16 + h) * 2048 + t) * 64 + d;
          u16 bits = f2bf(acc[i][j][r]);
          if (s == 0) qo[idx] = bits;
          else if (s == 1) ko[idx] = bits;
          else vo[idx] = bits;
        } else {
          outf[(size_t)row * 1024 + col] = acc[i][j][r];
        }
      }
}

// ------------------------- RoPE (in-place on q,k); folds softmax scale 0.125 into q (exact in bf16)
__global__ __launch_bounds__(256) void rope_kernel(u16* __restrict__ q, u16* __restrict__ k) {
  const int tx = threadIdx.x & 31, ty = threadIdx.x >> 5;
  const int t = blockIdx.x * 8 + ty;
  const int bh = blockIdx.y;
  float inv = powf(10000.f, -(float)tx * (1.f / 32.f));
  float ang = (float)t * inv;
  float s, c;
  sincosf(ang, &s, &c);
  size_t base = ((size_t)bh * 2048 + t) * 64;
  float a1 = bf2f(q[base + tx]), a2 = bf2f(q[base + tx + 32]);
  q[base + tx] = f2bf((a1 * c - a2 * s) * 0.125f);
  q[base + tx + 32] = f2bf((a2 * c + a1 * s) * 0.125f);
  float b1 = bf2f(k[base + tx]), b2 = bf2f(k[base + tx + 32]);
  k[base + tx] = f2bf(b1 * c - b2 * s);
  k[base + tx + 32] = f2bf(b2 * c + b1 * s);
}

// ------------------------------------------------- V transpose: [BH][T][64] -> [BH][64][T]
__global__ __launch_bounds__(256) void transpose_v(const u16* __restrict__ v,
                                                   u16* __restrict__ vt) {
  const int bh = blockIdx.y, t0 = blockIdx.x * 64;
  __shared__ __align__(16) u16 tile[64][72];
  const int tid = threadIdx.x;
  const int row = tid >> 3, col = (tid & 7) * 8;
#pragma unroll
  for (int rr = 0; rr < 2; ++rr) {
    int r = row + rr * 32;
    *(u16x8*)(&tile[r][col]) = *(const u16x8*)(v + ((size_t)bh * 2048 + t0 + r) * 64 + col);
  }
  __syncthreads();
#pragma unroll
  for (int rr = 0; rr < 2; ++rr) {
    int d = row + rr * 32;
    u16x8 o;
#pragma unroll
    for (int j = 0; j < 8; ++j) o[j] = tile[col + j][d];
    *(u16x8*)(vt + ((size_t)bh * 64 + d) * 2048 + t0 + col) = o;
  }
}

// --------------------------------------------------------- flash attention (causal), transposed-score form
// S^T = K.Q^T so q-rows land on C-layout cols (lane-aligned softmax state, 2 shuffles per reduction).
// O^T = V^T.P^T accumulates [d][q]. Q tile 128 (4 waves x 32 rows), K tile 64.
template <bool MASKED>
DEV void attn_tile(int kb, int q0w, int quad, int l15,
                   const u16* Ks, const u16* Vs, u16* Pw,
                   const bf16x8 qb_[2][2], f32x4 o[4][2], float* mi, float* li) {
  f32x4 st[4][2];
#pragma unroll
  for (int kf = 0; kf < 4; ++kf) {
    const int key = kf * 16 + l15;
    const int sw = key & 7;
    bf16x8 a0 = *(const bf16x8*)(Ks + key * 64 + ((quad ^ sw) * 8));
    bf16x8 a1 = *(const bf16x8*)(Ks + key * 64 + (((quad + 4) ^ sw) * 8));
#pragma unroll
    for (int qf = 0; qf < 2; ++qf) {
      f32x4 s = f32x4{0.f, 0.f, 0.f, 0.f};
      s = __builtin_amdgcn_mfma_f32_16x16x32_bf16(a0, qb_[qf][0], s, 0, 0, 0);
      s = __builtin_amdgcn_mfma_f32_16x16x32_bf16(a1, qb_[qf][1], s, 0, 0, 0);
      st[kf][qf] = s;
    }
  }
#pragma unroll
  for (int qf = 0; qf < 2; ++qf) {
    const int qrow = q0w + qf * 16 + l15;
    if (MASKED) {
#pragma unroll
      for (int kf = 0; kf < 4; ++kf)
#pragma unroll
        for (int r = 0; r < 4; ++r)
          if (kb + kf * 16 + quad * 4 + r > qrow) st[kf][qf][r] = -__builtin_inff();
    }
    float m = st[0][qf][0];
#pragma unroll
    for (int kf = 0; kf < 4; ++kf)
#pragma unroll
      for (int r = 0; r < 4; ++r) m = fmaxf(m, st[kf][qf][r]);
    m = fmaxf(m, __shfl_xor(m, 16, 64));
    m = fmaxf(m, __shfl_xor(m, 32, 64));
    const float mn = fmaxf(mi[qf], m);
    const float alpha = __expf(mi[qf] - mn);
    mi[qf] = mn;
    float rs = 0.f;
#pragma unroll
    for (int kf = 0; kf < 4; ++kf) {
      float p0 = __expf(st[kf][qf][0] - mn);
      float p1 = __expf(st[kf][qf][1] - mn);
      float p2 = __expf(st[kf][qf][2] - mn);
      float p3 = __expf(st[kf][qf][3] - mn);
      rs += (p0 + p1) + (p2 + p3);
      u16x4 pb = { f2bf(p0), f2bf(p1), f2bf(p2), f2bf(p3) };
      *(u16x4*)(Pw + (qf * 16 + l15) * 72 + kf * 16 + quad * 4) = pb;
    }
    rs += __shfl_xor(rs, 16, 64);
    rs += __shfl_xor(rs, 32, 64);
    li[qf] = li[qf] * alpha + rs;
#pragma unroll
    for (int df = 0; df < 4; ++df) o[df][qf] *= alpha;
  }
#pragma unroll
  for (int kk = 0; kk < 2; ++kk) {
    bf16x8 pb0 = *(const bf16x8*)(Pw + (0 * 16 + l15) * 72 + kk * 32 + quad * 8);
    bf16x8 pb1 = *(const bf16x8*)(Pw + (1 * 16 + l15) * 72 + kk * 32 + quad * 8);
#pragma unroll
    for (int df = 0; df < 4; ++df) {
      const int d = df * 16 + l15;
      bf16x8 va = *(const bf16x8*)(Vs + d * 64 + (((kk * 4 + quad) ^ (d & 7)) * 8));
      o[df][0] = __builtin_amdgcn_mfma_f32_16x16x32_bf16(va, pb0, o[df][0], 0, 0, 0);
      o[df][1] = __builtin_amdgcn_mfma_f32_16x16x32_bf16(va, pb1, o[df][1], 0, 0, 0);
    }
  }
}

__global__ __launch_bounds__(256) void attn_kernel(const u16* __restrict__ q,
                                                   const u16* __restrict__ k,
                                                   const u16* __restrict__ vt,
                                                   u16* __restrict__ y) {
  const int T = 2048;
  const int bh = blockIdx.x;                       // bh fastest: XCD sees bh%8==const -> K/V L2-resident
  const int qi = gridDim.y - 1 - blockIdx.y;       // long (diagonal-heavy) blocks dispatch first
  const int q0 = qi * 128;
  const int tid = threadIdx.x;
  const int w = tid >> 6, lane = tid & 63, quad = lane >> 4, l15 = lane & 15;
  __shared__ __align__(16) u16 Ks[64 * 64];        // [key][d], 16B-chunk xor-swizzled
  __shared__ __align__(16) u16 Vs[64 * 64];        // [d][key], 16B-chunk xor-swizzled
  __shared__ __align__(16) u16 Pq[4 * 32 * 72];    // per-wave P^T as [q][key], +8 pad
  u16* Pw = Pq + w * 32 * 72;

  const int q0w = q0 + w * 32;
  bf16x8 qb_[2][2];
#pragma unroll
  for (int qf = 0; qf < 2; ++qf)
#pragma unroll
    for (int h = 0; h < 2; ++h)
      qb_[qf][h] = *(const bf16x8*)(q + ((size_t)bh * T + q0w + qf * 16 + l15) * 64 + h * 32 + quad * 8);

  f32x4 o[4][2];
  float mi[2], li[2];
#pragma unroll
  for (int df = 0; df < 4; ++df)
#pragma unroll
    for (int qf = 0; qf < 2; ++qf) o[df][qf] = f32x4{0.f, 0.f, 0.f, 0.f};
  mi[0] = mi[1] = -__builtin_inff();
  li[0] = li[1] = 0.f;

  const int r_ = tid >> 3, c_ = tid & 7, sw_ = r_ & 7;
  const u16* kg = k + (size_t)bh * T * 64;
  const u16* vg = vt + (size_t)bh * 64 * T;
  const int nfull = q0 >> 6;

  for (int it = 0; it < nfull + 2; ++it) {
    const int kb = it * 64;
    gl_lds16(kg + (size_t)(kb + r_) * 64 + (c_ ^ sw_) * 8, Ks + tid * 8);
    gl_lds16(kg + (size_t)(kb + r_ + 32) * 64 + (c_ ^ sw_) * 8, Ks + 2048 + tid * 8);
    gl_lds16(vg + (size_t)r_ * T + kb + (c_ ^ sw_) * 8, Vs + tid * 8);
    gl_lds16(vg + (size_t)(r_ + 32) * T + kb + (c_ ^ sw_) * 8, Vs + 2048 + tid * 8);
    __syncthreads();
    if (it < nfull)
      attn_tile<false>(kb, q0w, quad, l15, Ks, Vs, Pw, qb_, o, mi, li);
    else
      attn_tile<true>(kb, q0w, quad, l15, Ks, Vs, Pw, qb_, o, mi, li);
    __syncthreads();
  }

  const int b = bh >> 4, h = bh & 15;
#pragma unroll
  for (int qf = 0; qf < 2; ++qf) {
    const float inv = 1.f / li[qf];
    const int t = q0w + qf * 16 + l15;
    const size_t base = ((size_t)b * 2048 + t) * 1024 + h * 64;
#pragma unroll
    for (int df = 0; df < 4; ++df) {
      u16x4 ov;
#pragma unroll
      for (int r = 0; r < 4; ++r) ov[r] = f2bf(o[df][qf][r] * inv);
      *(u16x4*)(y + base + df * 16 + quad * 4) = ov;
    }
  }
}

extern "C" void kernel_launch(void* const* d_in, const int* in_sizes, int n_in,
                              void* d_out, int out_size, void* d_ws, size_t ws_size,
                              hipStream_t stream) {
  const float* x = (const float*)d_in[0];
  const float* w_qkv = (const float*)d_in[1];
  const float* w_proj = (const float*)d_in[2];
  float* out = (float*)d_out;

  u16* xb = (u16*)d_ws;            // 8192*1024 bf16 (x), later reused as y
  u16* wqkvT = xb + 8388608;       // 3072*1024
  u16* wprojT = wqkvT + 3145728;   // 1024*1024
  u16* qb = wprojT + 1048576;      // [64][2048][64]
  u16* kbuf = qb + 8388608;
  u16* vb = kbuf + 8388608;
  u16* vtb = vb + 8388608;         // [64][64][2048]
  u16* yb = xb;                    // alias: xb fully consumed by gemm1 before attn writes y

  cast_f2b<<<8192, 256, 0, stream>>>(x, xb);
  transpose_cast<<<dim3(48, 16), 256, 0, stream>>>(w_qkv, wqkvT, 1024, 3072);
  transpose_cast<<<dim3(16, 16), 256, 0, stream>>>(w_proj, wprojT, 1024, 1024);
  gemm_bt<0><<<dim3(24, 64), 256, 0, stream>>>(xb, wqkvT, qb, kbuf, vb, nullptr);
  rope_kernel<<<dim3(256, 64), 256, 0, stream>>>(qb, kbuf);
  transpose_v<<<dim3(32, 64), 256, 0, stream>>>(vb, vtb);
  attn_kernel<<<dim3(64, 16), 256, 0, stream>>>(qb, kbuf, vtb, yb);
  gemm_bt<1><<<dim3(8, 64), 256, 0, stream>>>(yb, wprojT, nullptr, nullptr, nullptr, out);
}

// Round 3
// 295.358 us; speedup vs baseline: 1.8634x; 1.0526x over previous
//
#include <hip/hip_runtime.h>
#include <cstdint>

typedef unsigned short u16;
typedef __attribute__((ext_vector_type(4))) float f32x4;
typedef __attribute__((ext_vector_type(4))) unsigned short u16x4;
typedef __attribute__((ext_vector_type(8))) unsigned short u16x8;
typedef __attribute__((ext_vector_type(8))) __bf16 bf16x8;

#define DEV __device__ __forceinline__

DEV u16 f2bf(float f) {
  union { float f; uint32_t u; } x{f};
  uint32_t r = (x.u + 0x7fffu + ((x.u >> 16) & 1u)) >> 16;
  return (u16)r;
}

// async global->LDS, 16B per lane; LDS dest semantics: wave-uniform base + lane*16
DEV void gl_lds16(const void* g, void* l) {
  __builtin_amdgcn_global_load_lds((__attribute__((address_space(1))) void*)(g),
                                   (__attribute__((address_space(3))) void*)(l),
                                   16, 0, 0);
}

// ---------------------------------------------------------------- cast x -> bf16
__global__ __launch_bounds__(256) void cast_f2b(const float* __restrict__ in,
                                                u16* __restrict__ out) {
  int i = blockIdx.x * 256 + threadIdx.x;
  float4 v = ((const float4*)in)[i];
  u16x4 o = { f2bf(v.x), f2bf(v.y), f2bf(v.z), f2bf(v.w) };
  ((u16x4*)out)[i] = o;
}

// ------------------------------------------- transpose + cast weights: out[c][r] = in[r][c]
__global__ __launch_bounds__(256) void transpose_cast(const float* __restrict__ in,
                                                      u16* __restrict__ out, int R, int C) {
  __shared__ float tile[64][65];
  const int c0 = blockIdx.x * 64, r0 = blockIdx.y * 64;
  const int tx = threadIdx.x & 63, ty = threadIdx.x >> 6;
  for (int r = ty; r < 64; r += 4) tile[r][tx] = in[(size_t)(r0 + r) * C + c0 + tx];
  __syncthreads();
  for (int r = ty; r < 64; r += 4) out[(size_t)(c0 + r) * R + r0 + tx] = f2bf(tile[tx][r]);
}

// ------------------------------------------------------------- MFMA GEMM (A row-major, Bt row-major = B^T)
// EPI 0: C[8192][3072] -> split q/k/v bf16 head-major [BH][T][64], RoPE fused on q,k
//        (q additionally pre-scaled by 0.125*log2e so attention can use raw exp2)
// EPI 1: C[8192][1024] -> fp32 out
template <int EPI>
__global__ __launch_bounds__(256) void gemm_bt(const u16* __restrict__ A,
                                               const u16* __restrict__ Bt,
                                               u16* __restrict__ qo, u16* __restrict__ ko,
                                               u16* __restrict__ vo, float* __restrict__ outf) {
  const int K = 1024;
  __shared__ __align__(16) u16 As[128 * 32];
  __shared__ __align__(16) u16 Bs[128 * 32];
  const int m0 = blockIdx.y * 128, n0 = blockIdx.x * 128;
  const int tid = threadIdx.x;
  const int w = tid >> 6, lane = tid & 63, quad = lane >> 4, l15 = lane & 15;
  const int mw = (w >> 1) * 64, nw = (w & 1) * 64;
  const int srow = lane >> 2, scol = (lane & 3) * 8;

  f32x4 acc[4][4];
#pragma unroll
  for (int i = 0; i < 4; ++i)
#pragma unroll
    for (int j = 0; j < 4; ++j) acc[i][j] = f32x4{0.f, 0.f, 0.f, 0.f};

  const u16* ga0 = A + (size_t)(m0 + srow) * K + scol;
  const u16* gb0 = Bt + (size_t)(n0 + srow) * K + scol;

  for (int k0 = 0; k0 < K; k0 += 32) {
#pragma unroll
    for (int cc = 0; cc < 2; ++cc) {
      int c = w + cc * 4;
      gl_lds16(ga0 + (size_t)c * 16 * K + k0, As + c * 512 + lane * 8);
      gl_lds16(gb0 + (size_t)c * 16 * K + k0, Bs + c * 512 + lane * 8);
    }
    __syncthreads();
    bf16x8 af[4], bfv[4];
#pragma unroll
    for (int i = 0; i < 4; ++i)
      af[i] = *(const bf16x8*)(As + (mw + i * 16 + l15) * 32 + quad * 8);
#pragma unroll
    for (int j = 0; j < 4; ++j)
      bfv[j] = *(const bf16x8*)(Bs + (nw + j * 16 + l15) * 32 + quad * 8);
#pragma unroll
    for (int i = 0; i < 4; ++i)
#pragma unroll
      for (int j = 0; j < 4; ++j)
        acc[i][j] = __builtin_amdgcn_mfma_f32_16x16x32_bf16(af[i], bfv[j], acc[i][j], 0, 0, 0);
    __syncthreads();
  }

  // epilogue: C/D layout col = lane&15, row = quad*4 + r (verified m89/m91)
  if (EPI == 1) {
#pragma unroll
    for (int i = 0; i < 4; ++i)
#pragma unroll
      for (int j = 0; j < 4; ++j)
#pragma unroll
        for (int r = 0; r < 4; ++r) {
          int row = m0 + mw + i * 16 + quad * 4 + r;
          int col = n0 + nw + j * 16 + l15;
          outf[(size_t)row * 1024 + col] = acc[i][j][r];
        }
    return;
  }
  // EPI 0: n0 is 128-aligned within a 1024-wide section -> s, h wave-uniform
  const int s = n0 >> 10;                    // 0=q, 1=k, 2=v
  const int hh = ((n0 & 1023) + nw) >> 6;    // head index (wave-uniform)
  if (s == 2) {
#pragma unroll
    for (int i = 0; i < 4; ++i)
#pragma unroll
      for (int r = 0; r < 4; ++r) {
        int row = m0 + mw + i * 16 + quad * 4 + r;
        int b = row >> 11, t = row & 2047;
        size_t base = ((size_t)(b * 16 + hh) * 2048 + t) * 64;
#pragma unroll
        for (int j = 0; j < 4; ++j) vo[base + j * 16 + l15] = f2bf(acc[i][j][r]);
      }
  } else {
    u16* dst = (s == 0) ? qo : ko;
    const float QS = (s == 0) ? 0.18033688011112042f : 1.0f;  // 0.125*log2(e) for q
    const float C1 = -0.4152410118609203f;                    // -log2(10000)/32
    const float R2PI = 0.15915494309189535f;
    const float inv0 = __builtin_amdgcn_exp2f((float)l15 * C1) * R2PI;         // d = l15
    const float inv1 = __builtin_amdgcn_exp2f((float)(16 + l15) * C1) * R2PI;  // d = 16+l15
#pragma unroll
    for (int i = 0; i < 4; ++i)
#pragma unroll
      for (int r = 0; r < 4; ++r) {
        int row = m0 + mw + i * 16 + quad * 4 + r;
        int b = row >> 11, t = row & 2047;
        size_t base = ((size_t)(b * 16 + hh) * 2048 + t) * 64;
        float tf = (float)t;
        float a0 = tf * inv0; a0 -= floorf(a0);
        float a1 = tf * inv1; a1 -= floorf(a1);
        float c0 = __builtin_amdgcn_cosf(a0), s0 = __builtin_amdgcn_sinf(a0);
        float c1 = __builtin_amdgcn_cosf(a1), s1 = __builtin_amdgcn_sinf(a1);
        float x0 = acc[i][0][r], y0 = acc[i][2][r];
        float x1 = acc[i][1][r], y1 = acc[i][3][r];
        dst[base + l15]      = f2bf((x0 * c0 - y0 * s0) * QS);
        dst[base + 32 + l15] = f2bf((y0 * c0 + x0 * s0) * QS);
        dst[base + 16 + l15] = f2bf((x1 * c1 - y1 * s1) * QS);
        dst[base + 48 + l15] = f2bf((y1 * c1 + x1 * s1) * QS);
      }
  }
}

// ------------------------------------------------- V transpose: [BH][T][64] -> [BH][64][T]
__global__ __launch_bounds__(256) void transpose_v(const u16* __restrict__ v,
                                                   u16* __restrict__ vt) {
  const int bh = blockIdx.y, t0 = blockIdx.x * 64;
  __shared__ __align__(16) u16 tile[64][72];
  const int tid = threadIdx.x;
  const int row = tid >> 3, col = (tid & 7) * 8;
#pragma unroll
  for (int rr = 0; rr < 2; ++rr) {
    int r = row + rr * 32;
    *(u16x8*)(&tile[r][col]) = *(const u16x8*)(v + ((size_t)bh * 2048 + t0 + r) * 64 + col);
  }
  __syncthreads();
#pragma unroll
  for (int rr = 0; rr < 2; ++rr) {
    int d = row + rr * 32;
    u16x8 o;
#pragma unroll
    for (int j = 0; j < 8; ++j) o[j] = tile[col + j][d];
    *(u16x8*)(vt + ((size_t)bh * 64 + d) * 2048 + t0 + col) = o;
  }
}

// --------------------------------------------------------- flash attention (causal), transposed-score form
// S^T = K.Q^T (q pre-scaled by 0.125*log2e -> raw exp2 softmax). O^T = V^T.P^T.
// Q tile 64 (4 waves x 16 rows); K tile 64. Each block runs two q-tiles (qi, 31-qi)
// -> uniform 33 tile-iterations per block, 1024 blocks, 4/CU steady residency.
__global__ __launch_bounds__(256) void attn_kernel(const u16* __restrict__ q,
                                                   const u16* __restrict__ k,
                                                   const u16* __restrict__ vt,
                                                   u16* __restrict__ y) {
  const int T = 2048;
  const int bh = blockIdx.x;                 // bh fastest -> XCD L2 affinity for K/V
  const int pair = blockIdx.y;               // 0..15
  const int tid = threadIdx.x;
  const int w = tid >> 6, lane = tid & 63, quad = lane >> 4, l15 = lane & 15;
  __shared__ __align__(16) u16 Ks[64 * 64];  // [key][d], 16B-chunk xor-swizzled
  __shared__ __align__(16) u16 Vs[64 * 64];  // [d][key], 16B-chunk xor-swizzled
  __shared__ __align__(16) u16 Pq[4 * 16 * 72];
  u16* Pw = Pq + w * 16 * 72;

  // -------- loop-invariant LDS offsets (elements) --------
  const int sw = l15 & 7;
  int koffA[4], koffB[4];
#pragma unroll
  for (int kf = 0; kf < 4; ++kf) {
    const int key = kf * 16 + l15;
    koffA[kf] = key * 64 + ((quad ^ sw) * 8);
    koffB[kf] = key * 64 + (((quad + 4) ^ sw) * 8);
  }
  int voff[4][2];
#pragma unroll
  for (int df = 0; df < 4; ++df) {
    const int d = df * 16 + l15;
#pragma unroll
    for (int kk = 0; kk < 2; ++kk) voff[df][kk] = d * 64 + (((kk * 4 + quad) ^ sw) * 8);
  }
  const int pwoff = l15 * 72 + quad * 4;
  const int proff0 = l15 * 72 + quad * 8;
  const int proff1 = l15 * 72 + 32 + quad * 8;

  const int r_ = tid >> 3, c_ = tid & 7, ssw = r_ & 7;
  const u16* kg = k + (size_t)bh * T * 64;
  const u16* vg = vt + (size_t)bh * 64 * T;
  const int sk0 = r_ * 64 + (c_ ^ ssw) * 8;
  const int sk1 = (r_ + 32) * 64 + (c_ ^ ssw) * 8;
  const int sv0 = r_ * T + (c_ ^ ssw) * 8;
  const int sv1 = (r_ + 32) * T + (c_ ^ ssw) * 8;

  const int b_ = bh >> 4, h_ = bh & 15;

  for (int task = 0; task < 2; ++task) {
    const int qi = task ? pair : 31 - pair;  // long task first
    const int q0w = qi * 64 + w * 16;
    const u16* qp = q + ((size_t)bh * T + q0w + l15) * 64;
    const bf16x8 qf0 = *(const bf16x8*)(qp + quad * 8);
    const bf16x8 qf1 = *(const bf16x8*)(qp + 32 + quad * 8);

    f32x4 o[4];
#pragma unroll
    for (int df = 0; df < 4; ++df) o[df] = f32x4{0.f, 0.f, 0.f, 0.f};
    float mi = -__builtin_inff(), li = 0.f;
    const int nit = qi + 1;
    const int qrow = q0w + l15;

    for (int it = 0; it < nit; ++it) {
      const int kb = it * 64;
      gl_lds16(kg + (size_t)kb * 64 + sk0, Ks + tid * 8);
      gl_lds16(kg + (size_t)kb * 64 + sk1, Ks + 2048 + tid * 8);
      gl_lds16(vg + kb + sv0, Vs + tid * 8);
      gl_lds16(vg + kb + sv1, Vs + 2048 + tid * 8);
      __syncthreads();

      f32x4 st[4];
#pragma unroll
      for (int kf = 0; kf < 4; ++kf) {
        bf16x8 a0 = *(const bf16x8*)(Ks + koffA[kf]);
        bf16x8 a1 = *(const bf16x8*)(Ks + koffB[kf]);
        f32x4 s = f32x4{0.f, 0.f, 0.f, 0.f};
        s = __builtin_amdgcn_mfma_f32_16x16x32_bf16(a0, qf0, s, 0, 0, 0);
        s = __builtin_amdgcn_mfma_f32_16x16x32_bf16(a1, qf1, s, 0, 0, 0);
        st[kf] = s;
      }
      if (it == nit - 1) {  // diagonal tile: causal mask
#pragma unroll
        for (int kf = 0; kf < 4; ++kf)
#pragma unroll
          for (int r = 0; r < 4; ++r)
            if (kb + kf * 16 + quad * 4 + r > qrow) st[kf][r] = -__builtin_inff();
      }
      float m = st[0][0];
#pragma unroll
      for (int kf = 0; kf < 4; ++kf)
#pragma unroll
        for (int r = 0; r < 4; ++r) m = fmaxf(m, st[kf][r]);
      m = fmaxf(m, __shfl_xor(m, 16, 64));
      m = fmaxf(m, __shfl_xor(m, 32, 64));
      const float mn = fmaxf(mi, m);
      const float alpha = __builtin_amdgcn_exp2f(mi - mn);
      mi = mn;
      float rs = 0.f;
#pragma unroll
      for (int kf = 0; kf < 4; ++kf) {
        float p0 = __builtin_amdgcn_exp2f(st[kf][0] - mn);
        float p1 = __builtin_amdgcn_exp2f(st[kf][1] - mn);
        float p2 = __builtin_amdgcn_exp2f(st[kf][2] - mn);
        float p3 = __builtin_amdgcn_exp2f(st[kf][3] - mn);
        rs += (p0 + p1) + (p2 + p3);
        union { float f; uint32_t u; } u0{p0}, u1{p1}, u2{p2}, u3{p3};
        uint32_t pk01 = __builtin_amdgcn_perm(u1.u + 0x8000u, u0.u + 0x8000u, 0x07060302u);
        uint32_t pk23 = __builtin_amdgcn_perm(u3.u + 0x8000u, u2.u + 0x8000u, 0x07060302u);
        uint2 pk; pk.x = pk01; pk.y = pk23;
        *(uint2*)(Pw + pwoff + kf * 16) = pk;   // same-wave LDS RAW, no barrier needed
      }
      rs += __shfl_xor(rs, 16, 64);
      rs += __shfl_xor(rs, 32, 64);
      li = li * alpha + rs;
#pragma unroll
      for (int df = 0; df < 4; ++df) o[df] *= alpha;
      bf16x8 pb0 = *(const bf16x8*)(Pw + proff0);
      bf16x8 pb1 = *(const bf16x8*)(Pw + proff1);
#pragma unroll
      for (int df = 0; df < 4; ++df) {
        bf16x8 va0 = *(const bf16x8*)(Vs + voff[df][0]);
        bf16x8 va1 = *(const bf16x8*)(Vs + voff[df][1]);
        o[df] = __builtin_amdgcn_mfma_f32_16x16x32_bf16(va0, pb0, o[df], 0, 0, 0);
        o[df] = __builtin_amdgcn_mfma_f32_16x16x32_bf16(va1, pb1, o[df], 0, 0, 0);
      }
      __syncthreads();
    }

    const float inv = 1.f / li;
    const size_t base = ((size_t)b_ * 2048 + q0w + l15) * 1024 + h_ * 64;
#pragma unroll
    for (int df = 0; df < 4; ++df) {
      u16x4 ov;
#pragma unroll
      for (int r = 0; r < 4; ++r) ov[r] = f2bf(o[df][r] * inv);
      *(u16x4*)(y + base + df * 16 + quad * 4) = ov;
    }
  }
}

extern "C" void kernel_launch(void* const* d_in, const int* in_sizes, int n_in,
                              void* d_out, int out_size, void* d_ws, size_t ws_size,
                              hipStream_t stream) {
  const float* x = (const float*)d_in[0];
  const float* w_qkv = (const float*)d_in[1];
  const float* w_proj = (const float*)d_in[2];
  float* out = (float*)d_out;

  u16* xb = (u16*)d_ws;            // 8192*1024 bf16 (x), later reused as y
  u16* wqkvT = xb + 8388608;       // 3072*1024
  u16* wprojT = wqkvT + 3145728;   // 1024*1024
  u16* qb = wprojT + 1048576;      // [64][2048][64]
  u16* kbuf = qb + 8388608;
  u16* vb = kbuf + 8388608;
  u16* vtb = vb + 8388608;         // [64][64][2048]
  u16* yb = xb;                    // alias: xb fully consumed by gemm1 before attn writes y

  cast_f2b<<<8192, 256, 0, stream>>>(x, xb);
  transpose_cast<<<dim3(48, 16), 256, 0, stream>>>(w_qkv, wqkvT, 1024, 3072);
  transpose_cast<<<dim3(16, 16), 256, 0, stream>>>(w_proj, wprojT, 1024, 1024);
  gemm_bt<0><<<dim3(24, 64), 256, 0, stream>>>(xb, wqkvT, qb, kbuf, vb, nullptr);
  transpose_v<<<dim3(32, 64), 256, 0, stream>>>(vb, vtb);
  attn_kernel<<<dim3(64, 16), 256, 0, stream>>>(qb, kbuf, vtb, yb);
  gemm_bt<1><<<dim3(8, 64), 256, 0, stream>>>(yb, wprojT, nullptr, nullptr, nullptr, out);
}